// Round 4
// baseline (289.613 us; speedup 1.0000x reference)
//
#include <hip/hip_runtime.h>
#include <hip/hip_bf16.h>
#include <stdint.h>

#define B_ROWS 16384
#define D_K    2048
#define C_COLS 1000
#define C_PAD  1024
#define EPS_D2 1e-12f

// GEMM geometry: 256x256 tile, BK=64, 8 waves (2M x 4N), m201 8-phase schedule.
// LDS: 8 half-slots of 16 KiB: A[buf][kh] at buf*64K + kh*16K,
//                              B[buf][kh] at buf*64K + 32K + kh*16K.
#define BM 256
#define BN 256
#define NIT (D_K / 128)        // 16 iterations, 2 K-tiles (BK=64) each

typedef __attribute__((ext_vector_type(8))) short bf16x8;
typedef __attribute__((ext_vector_type(4))) float f32x4;

__device__ __forceinline__ void async16(void* lds, const void* g) {
    __builtin_amdgcn_global_load_lds(
        (const __attribute__((address_space(1))) unsigned int*)g,
        (__attribute__((address_space(3))) unsigned int*)lds,
        16, 0, 0);
}

// 4 f32 -> 4 bf16 (RNE) packed into uint2
__device__ __forceinline__ uint2 pack_bf16x4(float4 v) {
    union { __hip_bfloat162 h; uint32_t u; } a, b;
    a.h = __float22bfloat162_rn(make_float2(v.x, v.y));
    b.h = __float22bfloat162_rn(make_float2(v.z, v.w));
    uint2 r; r.x = a.u; r.y = b.u; return r;
}

// Wave-per-row prep: fp32 -> bf16 (RNE) + fp32 sum-of-squares. (unchanged)
__global__ __launch_bounds__(256) void prep_all(
    const float* __restrict__ x, const float* __restrict__ w,
    __hip_bfloat16* __restrict__ xb, __hip_bfloat16* __restrict__ wb,
    float* __restrict__ x2, float* __restrict__ w2) {
    const int t = threadIdx.x;
    const int wave = t >> 6;
    const int lane = t & 63;
    const int row = blockIdx.x * 4 + wave;

    const float* src;
    uint4* dst;
    float* norm_out;
    bool valid;
    if (row < B_ROWS) {
        src = x + (size_t)row * D_K;
        dst = (uint4*)(xb + (size_t)row * D_K);
        norm_out = x2 + row;
        valid = true;
    } else {
        int c = row - B_ROWS;
        src = w + (size_t)c * D_K;
        dst = (uint4*)(wb + (size_t)c * D_K);
        norm_out = w2 + c;
        valid = (c < C_COLS);
    }

    float4 v[8];
    if (valid) {
        const float4* s4 = (const float4*)src;
        #pragma unroll
        for (int i = 0; i < 4; i++) {
            v[2 * i]     = s4[2 * lane + 128 * i];
            v[2 * i + 1] = s4[2 * lane + 1 + 128 * i];
        }
    } else {
        #pragma unroll
        for (int i = 0; i < 8; i++) v[i] = make_float4(0.f, 0.f, 0.f, 0.f);
    }

    float ss = 0.f;
    #pragma unroll
    for (int i = 0; i < 8; i++)
        ss += v[i].x * v[i].x + v[i].y * v[i].y + v[i].z * v[i].z + v[i].w * v[i].w;

    #pragma unroll
    for (int i = 0; i < 4; i++) {
        uint2 a = pack_bf16x4(v[2 * i]);
        uint2 b = pack_bf16x4(v[2 * i + 1]);
        uint4 p; p.x = a.x; p.y = a.y; p.z = b.x; p.w = b.y;
        dst[lane + 64 * i] = p;
    }

    #pragma unroll
    for (int off = 32; off > 0; off >>= 1) ss += __shfl_down(ss, off, 64);
    if (lane == 0 && valid) *norm_out = ss;
}

// ---- m201 8-phase template helpers ----
#define SLOT(buf, kh) ((buf) * 65536 + (kh) * 16384)

#define SA(buf, kh, t) { \
    async16(lA0 + SLOT(buf, kh), gA0 + (t) * 64 + (kh) * 32); \
    async16(lA1 + SLOT(buf, kh), gA1 + (t) * 64 + (kh) * 32); }

#define SB(buf, kh, t) { \
    async16(lB0 + SLOT(buf, kh), gB0 + (t) * 64 + (kh) * 32); \
    async16(lB1 + SLOT(buf, kh), gB1 + (t) * 64 + (kh) * 32); }

#define RD_B(buf, kh) { \
    b[0] = *(const bf16x8*)(fB + SLOT(buf, kh)); \
    b[1] = *(const bf16x8*)(fB + SLOT(buf, kh) + 1024); \
    b[2] = *(const bf16x8*)(fB + SLOT(buf, kh) + 2048); \
    b[3] = *(const bf16x8*)(fB + SLOT(buf, kh) + 3072); }

#define RD_A(buf, kh, mh) { \
    a[0] = *(const bf16x8*)(fA + SLOT(buf, kh) + (mh) * 4096); \
    a[1] = *(const bf16x8*)(fA + SLOT(buf, kh) + (mh) * 4096 + 1024); \
    a[2] = *(const bf16x8*)(fA + SLOT(buf, kh) + (mh) * 4096 + 2048); \
    a[3] = *(const bf16x8*)(fA + SLOT(buf, kh) + (mh) * 4096 + 3072); }

#define SYNC_IN { \
    __builtin_amdgcn_s_barrier(); \
    asm volatile("s_waitcnt lgkmcnt(0)" ::: "memory"); \
    __builtin_amdgcn_sched_barrier(0); }

#define MFMA_BLK(base) { \
    __builtin_amdgcn_s_setprio(1); \
    _Pragma("unroll") \
    for (int i = 0; i < 4; ++i) \
        _Pragma("unroll") \
        for (int q = 0; q < 4; ++q) \
            acc[(base) + i][q] = __builtin_amdgcn_mfma_f32_16x16x32_bf16(a[i], b[q], acc[(base) + i][q], 0, 0, 0); \
    __builtin_amdgcn_s_setprio(0); }

#define SYNC_OUT __builtin_amdgcn_s_barrier();

// 256x256 tile, BK=64x2 per iter, 512 threads = 8 waves (2Mx4N), wave tile 128x64.
// m201 8-phase: phase = {ds_reads (8 or 4) ; stage 1 half-slot (2 gload_lds) ;
// barrier ; lgkmcnt(0) ; setprio(1) 16xMFMA setprio(0) ; barrier}; vmcnt(6)
// only at phases 4 and 8. Half-slots split along K; B-frags register-reused
// across the two mh-phases. XOR chunk swizzle (0 conflicts).
__global__ __launch_bounds__(512, 2) void dml_gemm(
    const __hip_bfloat16* __restrict__ A,   // [B_ROWS, D_K] bf16
    const __hip_bfloat16* __restrict__ Bm,  // [C_PAD, D_K] bf16 (padded)
    const float* __restrict__ x2, const float* __restrict__ w2,
    const float* __restrict__ scales, float* __restrict__ out)
{
    __shared__ __align__(16) char smem[131072];

    const int tid  = threadIdx.x;
    const int wave = tid >> 6;
    const int lane = tid & 63;
    const int wm = wave >> 2;     // 0..1
    const int wn = wave & 3;      // 0..3

    // XCD-chunked mapping: 256 blocks = 1/CU; XCD x owns m-tiles [8x, 8x+8) x all 4 n.
    const int id  = blockIdx.x;
    const int xcd = id & 7;
    const int j5  = id >> 3;
    const int m0  = (xcd * 8 + (j5 & 7)) * BM;
    const int n0  = (j5 >> 3) * BN;

    // ---- staging geometry: per half-slot 1024 16B-chunks; 2 per thread.
    // chunk L: row r = L>>2, stored pos c = L&3 holds k-chunk g = c ^ ((r>>1)&3)
    const int L0 = tid, L1 = tid + 512;
    const int r0 = L0 >> 2, g0 = (L0 & 3) ^ ((r0 >> 1) & 3);
    const int r1 = L1 >> 2, g1 = (L1 & 3) ^ ((r1 >> 1) & 3);
    const __hip_bfloat16* gA0 = A  + (size_t)(m0 + r0) * D_K + g0 * 8;
    const __hip_bfloat16* gA1 = A  + (size_t)(m0 + r1) * D_K + g1 * 8;
    const __hip_bfloat16* gB0 = Bm + (size_t)(n0 + r0) * D_K + g0 * 8;
    const __hip_bfloat16* gB1 = Bm + (size_t)(n0 + r1) * D_K + g1 * 8;
    char* lA0 = smem + L0 * 16;
    char* lA1 = smem + L1 * 16;
    char* lB0 = smem + 32768 + L0 * 16;
    char* lB1 = smem + 32768 + L1 * 16;

    // ---- fragment read ptrs (row = 64 B, 4 chunks; swizzled chunk = fq ^ ((fr>>1)&3))
    // Swizzle term depends only on fr (row steps of 16/64 don't change (row>>1)&3).
    const int fr = lane & 15;
    const int fq = lane >> 4;
    const int swz = (fq ^ ((fr >> 1) & 3)) * 16;
    const char* fA = smem + (wm * 128 + fr) * 64 + swz;          // + SLOT + mh*4096 + mi*1024
    const char* fB = smem + 32768 + (wn * 64 + fr) * 64 + swz;   // + SLOT + q*1024

    f32x4 acc[8][4] = {};

    // ---- prologue: stage 7 half-slots (A00,B00,A01,B01 <- tile0; A10,B10,B11 <- tile1).
    // A11 <- tile1 is staged by iter0's P1 (steady-state pattern).
    SA(0, 0, 0); SB(0, 0, 0); SA(0, 1, 0); SB(0, 1, 0);
    SA(1, 0, 1); SB(1, 0, 1); SB(1, 1, 1);
    asm volatile("s_waitcnt vmcnt(0)" ::: "memory");
    __builtin_amdgcn_s_barrier();
    __builtin_amdgcn_sched_barrier(0);

    // ---- main loop: iter it computes K-tiles 2it (buf0) and 2it+1 (buf1).
    // Phase p stages the half-slot freed at phase p-1, for its next consumer.
    #pragma unroll 1
    for (int it = 0; it < NIT; ++it) {
        const int t2 = 2 * it + 2, t3 = 2 * it + 3;
        const bool st = (it < NIT - 1);
        bf16x8 a[4], b[4];

        // P1: buf0 kh0 mh0 | reads 4a+4b | stage A[1][1] <- tile 2it+1
        RD_B(0, 0); RD_A(0, 0, 0);
        SA(1, 1, 2 * it + 1);
        SYNC_IN; MFMA_BLK(0); SYNC_OUT;

        // P2: buf0 kh0 mh1 | reads 4a (b reused) | stage B[0][0] <- t2
        RD_A(0, 0, 1);
        if (st) SB(0, 0, t2);
        SYNC_IN; MFMA_BLK(4); SYNC_OUT;

        // P3: buf0 kh1 mh0 | reads 4a+4b | stage A[0][0] <- t2
        RD_B(0, 1); RD_A(0, 1, 0);
        if (st) SA(0, 0, t2);
        SYNC_IN; MFMA_BLK(0); SYNC_OUT;

        // P4: buf0 kh1 mh1 | reads 4a | stage B[0][1] <- t2 | vmcnt checkpoint
        RD_A(0, 1, 1);
        if (st) SB(0, 1, t2);
        SYNC_IN; MFMA_BLK(4);
        if (st) asm volatile("s_waitcnt vmcnt(6)" ::: "memory");
        else    asm volatile("s_waitcnt vmcnt(0)" ::: "memory");
        SYNC_OUT;

        // P5: buf1 kh0 mh0 | reads 4a+4b | stage A[0][1] <- t2
        RD_B(1, 0); RD_A(1, 0, 0);
        if (st) SA(0, 1, t2);
        SYNC_IN; MFMA_BLK(0); SYNC_OUT;

        // P6: buf1 kh0 mh1 | reads 4a | stage B[1][0] <- t3
        RD_A(1, 0, 1);
        if (st) SB(1, 0, t3);
        SYNC_IN; MFMA_BLK(4); SYNC_OUT;

        // P7: buf1 kh1 mh0 | reads 4a+4b | stage A[1][0] <- t3
        RD_B(1, 1); RD_A(1, 1, 0);
        if (st) SA(1, 0, t3);
        SYNC_IN; MFMA_BLK(0); SYNC_OUT;

        // P8: buf1 kh1 mh1 | reads 4a | stage B[1][1] <- t3 | vmcnt checkpoint
        RD_A(1, 1, 1);
        if (st) SB(1, 1, t3);
        SYNC_IN; MFMA_BLK(4);
        if (st) asm volatile("s_waitcnt vmcnt(6)" ::: "memory");
        SYNC_OUT;
    }

    // ---- epilogue: -s*sqrt(max(x2+w2-2*acc, eps)); direct stores.
    // C/D layout: col = lane&15 (n-side), row = (lane>>4)*4 + reg (m-side).
    const float s = scales[0];
    const int colb = n0 + wn * 64 + fr;
    const int rowb = m0 + wm * 128 + fq * 4;

    float w2v[4];
    #pragma unroll
    for (int q = 0; q < 4; ++q) w2v[q] = w2[colb + q * 16];

    #pragma unroll
    for (int i = 0; i < 8; ++i) {
        float x2v[4];
        #pragma unroll
        for (int r = 0; r < 4; ++r) x2v[r] = x2[rowb + i * 16 + r];
        #pragma unroll
        for (int q = 0; q < 4; ++q) {
            if (colb + q * 16 < C_COLS) {
                float* orow = out + (size_t)(rowb + i * 16) * C_COLS + colb + q * 16;
                #pragma unroll
                for (int r = 0; r < 4; ++r) {
                    float d2 = x2v[r] + w2v[q] - 2.0f * acc[i][q][r];
                    d2 = fmaxf(d2, EPS_D2);
                    orow[(size_t)r * C_COLS] = -s * __builtin_sqrtf(d2);
                }
            }
        }
    }
}

extern "C" void kernel_launch(void* const* d_in, const int* in_sizes, int n_in,
                              void* d_out, int out_size, void* d_ws, size_t ws_size,
                              hipStream_t stream) {
    const float* x      = (const float*)d_in[0];
    const float* w      = (const float*)d_in[1];
    const float* scales = (const float*)d_in[2];
    float* out = (float*)d_out;

    char* ws = (char*)d_ws;
    __hip_bfloat16* xb = (__hip_bfloat16*)ws;                                  // 67,108,864 B
    __hip_bfloat16* wb = (__hip_bfloat16*)(ws + (size_t)B_ROWS * D_K * 2);     //  4,194,304 B
    float* x2 = (float*)(ws + (size_t)B_ROWS * D_K * 2 + (size_t)C_PAD * D_K * 2);
    float* w2 = x2 + B_ROWS;

    prep_all<<<dim3((B_ROWS + C_PAD) / 4), dim3(256), 0, stream>>>(x, w, xb, wb, x2, w2);
    dml_gemm<<<dim3((B_ROWS / BM) * (C_PAD / BN)), dim3(512), 0, stream>>>(xb, wb, x2, w2, scales, out);
}